// Round 1
// baseline (63.364 us; speedup 1.0000x reference)
//
#include <hip/hip_runtime.h>

namespace {

constexpr int kB  = 8;
constexpr int kCF = 32;
constexpr int kCP = 4;
constexpr int kS  = 64;
constexpr int kL  = 32;
constexpr int kPlane = kS * kS;                       // 4096
constexpr long long kChStride = (long long)kS * kPlane; // 262144 floats per channel
constexpr int kMCos = kL * kPlane;                    // 131072 cos positions / sample
constexpr int kCosBlocksPerB = kMCos / (256 * 4);     // 128
constexpr int kKlElems = kCP * kL * kPlane;           // 524288 kl elements / sample
constexpr int kKlBlocksPerB = kKlElems / (256 * 4);   // 512
constexpr float kClampEps = 1e-6f;
constexpr float kCosEps = 1e-8f;

__device__ __forceinline__ float block_reduce_sum(float v) {
  #pragma unroll
  for (int off = 32; off > 0; off >>= 1) v += __shfl_down(v, off, 64);
  __shared__ float smem[4];
  const int lane = threadIdx.x & 63;
  const int wid  = threadIdx.x >> 6;
  if (lane == 0) smem[wid] = v;
  __syncthreads();
  float r = 0.f;
  if (threadIdx.x == 0) r = smem[0] + smem[1] + smem[2] + smem[3];
  __syncthreads();  // protect smem against a second call racing thread 0's read
  return r;
}

// One block = 1024 consecutive positions of one sample's cos slice.
// partial[blk] = sum over positions of num/den.
__global__ __launch_bounds__(256) void cos_kernel(
    const float* __restrict__ sf, const float* __restrict__ tf,
    const int* __restrict__ cur_start, const int* __restrict__ adj_start,
    float* __restrict__ partial) {
  const int blk   = blockIdx.x;
  const int b     = blk >> 7;                 // / kCosBlocksPerB
  const int chunk = blk & (kCosBlocksPerB - 1);
  const int cs = cur_start[b];
  const int as = adj_start[b];
  const int pos = chunk * 1024 + (int)threadIdx.x * 4;  // position in [0, 131072)
  const int dd  = pos >> 12;                  // / kPlane
  const int rem = pos & (kPlane - 1);
  const float* sp = sf + ((long long)b * kCF * kS + (cs + dd)) * kPlane + rem;
  const float* tq = tf + ((long long)b * kCF * kS + (as + dd)) * kPlane + rem;

  float4 dot = make_float4(0.f, 0.f, 0.f, 0.f);
  float4 na  = make_float4(0.f, 0.f, 0.f, 0.f);
  float4 nb  = make_float4(0.f, 0.f, 0.f, 0.f);
  #pragma unroll 8
  for (int c = 0; c < kCF; ++c) {
    const float4 a = *reinterpret_cast<const float4*>(sp + c * kChStride);
    const float4 t = *reinterpret_cast<const float4*>(tq + c * kChStride);
    dot.x += a.x * t.x; dot.y += a.y * t.y; dot.z += a.z * t.z; dot.w += a.w * t.w;
    na.x  += a.x * a.x; na.y  += a.y * a.y; na.z  += a.z * a.z; na.w  += a.w * a.w;
    nb.x  += t.x * t.x; nb.y  += t.y * t.y; nb.z  += t.z * t.z; nb.w  += t.w * t.w;
  }
  float local =
      dot.x / (fmaxf(sqrtf(na.x), kCosEps) * fmaxf(sqrtf(nb.x), kCosEps)) +
      dot.y / (fmaxf(sqrtf(na.y), kCosEps) * fmaxf(sqrtf(nb.y), kCosEps)) +
      dot.z / (fmaxf(sqrtf(na.z), kCosEps) * fmaxf(sqrtf(nb.z), kCosEps)) +
      dot.w / (fmaxf(sqrtf(na.w), kCosEps) * fmaxf(sqrtf(nb.w), kCosEps));
  const float s = block_reduce_sum(local);
  if (threadIdx.x == 0) partial[blk] = s;
}

__device__ __forceinline__ float kl_term(float sv, float tv) {
  const float sc = fminf(fmaxf(sv, kClampEps), 1.f - kClampEps);
  const float tc = fminf(fmaxf(tv, kClampEps), 1.f - kClampEps);
  return tc * (__logf(tc) - __logf(sc));
}

// One block = 1024 consecutive elements of one sample's KL slice.
__global__ __launch_bounds__(256) void kl_kernel(
    const float* __restrict__ sp, const float* __restrict__ tp,
    const int* __restrict__ cur_start, const int* __restrict__ adj_start,
    float* __restrict__ partial) {
  const int blk   = blockIdx.x;
  const int b     = blk >> 9;                 // / kKlBlocksPerB
  const int chunk = blk & (kKlBlocksPerB - 1);
  const int cs = cur_start[b];
  const int as = adj_start[b];
  const int pos = chunk * 1024 + (int)threadIdx.x * 4;  // in [0, 524288)
  const int c   = pos >> 17;                  // / kMCos
  const int m   = pos & (kMCos - 1);
  const int dd  = m >> 12;
  const int rem = m & (kPlane - 1);
  const float4 s4 = *reinterpret_cast<const float4*>(
      sp + ((long long)(b * kCP + c) * kS + (cs + dd)) * kPlane + rem);
  const float4 t4 = *reinterpret_cast<const float4*>(
      tp + ((long long)(b * kCP + c) * kS + (as + dd)) * kPlane + rem);
  const float local = kl_term(s4.x, t4.x) + kl_term(s4.y, t4.y) +
                      kl_term(s4.z, t4.z) + kl_term(s4.w, t4.w);
  const float ssum = block_reduce_sum(local);
  if (threadIdx.x == 0) partial[kB * kCosBlocksPerB + blk] = ssum;
}

// Single block: fold all partials into the scalar loss.
__global__ __launch_bounds__(256) void final_kernel(
    const float* __restrict__ partial, float* __restrict__ out) {
  const int nCos = kB * kCosBlocksPerB;   // 1024
  const int nKl  = kB * kKlBlocksPerB;    // 4096
  float cosAcc = 0.f, klAcc = 0.f;
  for (int i = threadIdx.x; i < nCos; i += 256) cosAcc += partial[i];
  for (int i = threadIdx.x; i < nKl;  i += 256) klAcc  += partial[nCos + i];
  const float cosTot = block_reduce_sum(cosAcc);
  const float klTot  = block_reduce_sum(klAcc);
  if (threadIdx.x == 0) {
    // mean_b [ (1 - cos_sum_b/131072) + 0.3*kl_b ]
    out[0] = 1.f - cosTot / (float)(kB * kMCos) + 0.3f * klTot / (float)kB;
  }
}

}  // namespace

extern "C" void kernel_launch(void* const* d_in, const int* in_sizes, int n_in,
                              void* d_out, int out_size, void* d_ws, size_t ws_size,
                              hipStream_t stream) {
  const float* sf = (const float*)d_in[0];
  const float* tf = (const float*)d_in[1];
  const float* sp = (const float*)d_in[2];
  const float* tp = (const float*)d_in[3];
  const int* cur_start = (const int*)d_in[4];
  const int* adj_start = (const int*)d_in[5];
  float* out = (float*)d_out;
  float* partial = (float*)d_ws;  // needs (1024 + 4096) * 4 = 20480 bytes

  cos_kernel<<<kB * kCosBlocksPerB, 256, 0, stream>>>(sf, tf, cur_start, adj_start, partial);
  kl_kernel<<<kB * kKlBlocksPerB, 256, 0, stream>>>(sp, tp, cur_start, adj_start, partial);
  final_kernel<<<1, 256, 0, stream>>>(partial, out);
}